// Round 12
// baseline (74.532 us; speedup 1.0000x reference)
//
#include <hip/hip_runtime.h>
#include <cstdint>
#include <cstddef>

#define BB 32
#define NN 4096
#define DD 256
#define KK 16

constexpr int TILE  = 64;             // tokens per block
constexpr int TPBAT = NN / TILE;      // 64
constexpr int TILES = BB * TPBAT;     // 2048
constexpr float FEPS = 1e-12f;

__device__ __forceinline__ float dot4(float4 a, float4 b) {
  return a.x*b.x + a.y*b.y + a.z*b.z + a.w*b.w;
}
__device__ __forceinline__ float4 f4add(float4 a, float4 b) {
  return make_float4(a.x+b.x, a.y+b.y, a.z+b.z, a.w+b.w);
}
__device__ __forceinline__ float4 f4fma(float s, float4 x, float4 a) {
  a.x += s*x.x; a.y += s*x.y; a.z += s*x.z; a.w += s*x.w; return a;
}

// ---------------------------------------------------------------------------
// Fused kernel: 64-token tile fully resident in LDS (64 KB, XOR-swizzled
// f4 index j^row -> <=2-way banks everywhere = free). x read from global
// EXACTLY once. 256 threads, 2 blocks/CU (LDS-limited).
//   Stage : 16 f4 loads/thread -> swizzled ds_write.
//   PhaseA: thread = token (lane), wave = k-quad (scalar W via s_load);
//           full-row dot from LDS; softmax via psum exchange; al[64][20].
//   PhaseB: wave = k-quad, lane = dim-quad; x + al from LDS; acc = 4 f4.
// ---------------------------------------------------------------------------
__global__ __launch_bounds__(256, 2) void fused_kernel(
    const float* __restrict__ x, const int* __restrict__ mask,
    const float* __restrict__ W, const float* __restrict__ bias,
    float* __restrict__ outv, float* __restrict__ outs, int partial_mode)
{
  __shared__ float4 xs4[TILE * 64];   // 64 KB swizzled x tile
  __shared__ float  al[TILE * 20];    // 5 KB assigns (pad 16->20)
  __shared__ float  psum[TILE][4];    // 1 KB exp-sum partials
  __shared__ float  asacc[KK];        // 64 B assign-sums

  const int tid  = threadIdx.x;
  const int lane = tid & 63;          // Phase A: token. Phase B: dim-quad.
  const int wave = tid >> 6;
  const int kgr  = __builtin_amdgcn_readfirstlane(wave);  // k-quad id

  const int tile = blockIdx.x;
  const int b    = tile / TPBAT;
  const int n0   = (tile % TPBAT) * TILE;

  const float4* xb4 = reinterpret_cast<const float4*>(x + ((size_t)b*NN + n0)*DD);
  const int*    mb  = mask + (size_t)b*NN + n0;

  // ---------------- stage: 16 f4 per thread, swizzled ---------------------
  float4 sg[16];
#pragma unroll
  for (int q = 0; q < 16; ++q) sg[q] = xb4[q * 256 + tid];
  const int mv = mb[lane];
#pragma unroll
  for (int q = 0; q < 16; ++q) {
    const int r = q * 4 + wave;       // row written by this wave (uniform)
    xs4[r * 64 + (lane ^ r)] = sg[q];
  }
  __syncthreads();

  // ---------------- Phase A: 4 logits per thread (k = 4*kgr+q) ------------
  const float* Wk = W + (size_t)(kgr * 4) * DD;   // scalar base
  float part[4];
#pragma unroll
  for (int q = 0; q < 4; ++q) part[q] = bias[kgr * 4 + q];

#pragma unroll 8
  for (int jj = 0; jj < 64; ++jj) {
    const float4 xv = xs4[lane * 64 + (jj ^ lane)];
#pragma unroll
    for (int q = 0; q < 4; ++q) {
      const float4 wv = *reinterpret_cast<const float4*>(Wk + q * DD + jj * 4);
      part[q] += dot4(xv, wv);
    }
  }

  // masked softmax: exchange 4 per-k-quad exp-sums via psum
  float e[4], pexp = 0.f;
#pragma unroll
  for (int q = 0; q < 4; ++q) { e[q] = __expf(part[q]); pexp += e[q]; }
  psum[lane][kgr] = pexp;
  __syncthreads();
  {
    const float4 ps4 = *reinterpret_cast<const float4*>(&psum[lane][0]);
    const float denom = (ps4.x + ps4.y) + (ps4.z + ps4.w);
    const float r = mv ? (1.0f / denom) : 0.0f;
    float a0 = e[0]*r, a1 = e[1]*r, a2 = e[2]*r, a3 = e[3]*r;
    *reinterpret_cast<float4*>(&al[lane * 20 + kgr * 4]) =
        make_float4(a0, a1, a2, a3);
    // asum: butterfly over 64 lanes (= 64 distinct tokens)
    float r0 = a0, r1 = a1, r2 = a2, r3 = a3;
#pragma unroll
    for (int off = 32; off >= 1; off >>= 1) {
      r0 += __shfl_xor(r0, off); r1 += __shfl_xor(r1, off);
      r2 += __shfl_xor(r2, off); r3 += __shfl_xor(r3, off);
    }
    if (lane == 0) {
      asacc[kgr * 4 + 0] = r0; asacc[kgr * 4 + 1] = r1;
      asacc[kgr * 4 + 2] = r2; asacc[kgr * 4 + 3] = r3;
    }
  }
  __syncthreads();

  // ---------------- Phase B: acc[k-quad] over all 64 tokens, from LDS -----
  float4 acc0 = make_float4(0.f,0.f,0.f,0.f);
  float4 acc1 = acc0, acc2 = acc0, acc3 = acc0;
  const int kq4 = kgr * 4;

#pragma unroll 8
  for (int t = 0; t < TILE; ++t) {
    const float4 av = *reinterpret_cast<const float4*>(&al[t * 20 + kq4]);
    const float4 xv = xs4[t * 64 + (lane ^ t)];
    acc0 = f4fma(av.x, xv, acc0);
    acc1 = f4fma(av.y, xv, acc1);
    acc2 = f4fma(av.z, xv, acc2);
    acc3 = f4fma(av.w, xv, acc3);
  }

  // ---------------- output -------------------------------------------------
  if (partial_mode) {
    float4* dst = reinterpret_cast<float4*>(outv + (size_t)tile * KK * DD);
    dst[(kq4 + 0) * 64 + lane] = acc0;
    dst[(kq4 + 1) * 64 + lane] = acc1;
    dst[(kq4 + 2) * 64 + lane] = acc2;
    dst[(kq4 + 3) * 64 + lane] = acc3;
    if (tid < KK) outs[tile * KK + tid] = asacc[tid];
  } else {
    float* vb = outv + (size_t)b * KK * DD;
    const float4 aa4[4] = {acc0, acc1, acc2, acc3};
#pragma unroll
    for (int i = 0; i < 4; ++i) {
      float* p = vb + (kq4 + i) * DD + 4 * lane;
      atomicAdd(p + 0, aa4[i].x);
      atomicAdd(p + 1, aa4[i].y);
      atomicAdd(p + 2, aa4[i].z);
      atomicAdd(p + 3, aa4[i].w);
    }
    if (tid < KK) atomicAdd(&outs[b * KK + tid], asacc[tid]);
  }
}

// ---------------------------------------------------------------------------
// Finalize A (BB*KK blocks x 256 thr): block = (b,k). float4 slice-sum with
// 4 slice-groups x 4 accumulators, LDS combine, ssum by wave butterfly.
// ---------------------------------------------------------------------------
__global__ __launch_bounds__(256) void finalizeA_kernel(
    const float* __restrict__ pv, const float* __restrict__ ps,
    const float* __restrict__ cent, float* __restrict__ vtmp,
    float* __restrict__ ssbuf, int nslice)
{
  const int blk = blockIdx.x;
  const int b   = blk >> 4;
  const int k   = blk & 15;
  const int tid = threadIdx.x;
  const int sg  = tid >> 6;           // slice group 0..3
  const int ld  = tid & 63;           // float4 dim index

  __shared__ float4 cmbA[3][64];

  float pval = 0.f;
  for (int s = ld; s < nslice; s += 64)
    pval += ps[(size_t)(b * nslice + s) * KK + k];
#pragma unroll
  for (int off = 32; off >= 1; off >>= 1) pval += __shfl_xor(pval, off);
  const float ssum = pval;

  const float4* pv4 = reinterpret_cast<const float4*>(pv);
  const size_t base = ((size_t)b * nslice * KK + k) * 64 + ld;
  float4 a0 = make_float4(0.f,0.f,0.f,0.f), a1 = a0, a2 = a0, a3 = a0;
  int s = sg;
  for (; s + 12 < nslice; s += 16) {
    a0 = f4add(a0, pv4[base + (size_t)(s     ) * (KK * 64)]);
    a1 = f4add(a1, pv4[base + (size_t)(s +  4) * (KK * 64)]);
    a2 = f4add(a2, pv4[base + (size_t)(s +  8) * (KK * 64)]);
    a3 = f4add(a3, pv4[base + (size_t)(s + 12) * (KK * 64)]);
  }
  for (; s < nslice; s += 4)
    a0 = f4add(a0, pv4[base + (size_t)s * (KK * 64)]);
  float4 tot = f4add(f4add(a0, a1), f4add(a2, a3));

  if (sg > 0) cmbA[sg - 1][ld] = tot;
  __syncthreads();

  if (sg == 0) {
    tot = f4add(tot, f4add(cmbA[0][ld], f4add(cmbA[1][ld], cmbA[2][ld])));
    const float4 cv = reinterpret_cast<const float4*>(cent)[k * 64 + ld];
    float4 v;
    v.x = tot.x - ssum * cv.x;
    v.y = tot.y - ssum * cv.y;
    v.z = tot.z - ssum * cv.z;
    v.w = tot.w - ssum * cv.w;
    reinterpret_cast<float4*>(vtmp)[((size_t)b * KK + k) * 64 + ld] = v;
    float p = dot4(v, v);
#pragma unroll
    for (int off = 32; off >= 1; off >>= 1) p += __shfl_xor(p, off);
    if (ld == 0) ssbuf[blk] = p;
  }
}

// ---------------------------------------------------------------------------
// Finalize B (BB blocks x 1024 thr): intra-cluster + global L2 normalize.
// ---------------------------------------------------------------------------
__global__ __launch_bounds__(1024) void finalizeB_kernel(
    const float* __restrict__ vtmp, const float* __restrict__ ssbuf,
    float* __restrict__ out)
{
  const int b    = blockIdx.x;
  const int tid  = threadIdx.x;
  const int d    = tid & 255;
  const int kq   = tid >> 8;
  const int lane = tid & 63;
  const int w    = tid >> 6;

  __shared__ float redB[16];
  __shared__ float gsh;

  float u[4];
  float p2 = 0.f;
#pragma unroll
  for (int kk = 0; kk < 4; ++kk) {
    const int k = kq * 4 + kk;
    const float rk = 1.0f / fmaxf(sqrtf(ssbuf[b * KK + k]), FEPS);
    u[kk] = vtmp[((size_t)b * KK + k) * DD + d] * rk;
    p2 += u[kk] * u[kk];
  }
#pragma unroll
  for (int off = 32; off >= 1; off >>= 1) p2 += __shfl_xor(p2, off);
  if (lane == 0) redB[w] = p2;
  __syncthreads();

  if (tid == 0) {
    float g = 0.f;
#pragma unroll
    for (int i = 0; i < 16; ++i) g += redB[i];
    gsh = 1.0f / fmaxf(sqrtf(g), FEPS);
  }
  __syncthreads();

  const float g = gsh;
#pragma unroll
  for (int kk = 0; kk < 4; ++kk) {
    const int k = kq * 4 + kk;
    out[(size_t)b * KK * DD + k * DD + d] = u[kk] * g;
  }
}

extern "C" void kernel_launch(void* const* d_in, const int* in_sizes, int n_in,
                              void* d_out, int out_size, void* d_ws, size_t ws_size,
                              hipStream_t stream) {
  const float* x    = (const float*)d_in[0];
  const int*   mask = (const int*)d_in[1];
  const float* W    = (const float*)d_in[2];
  const float* bias = (const float*)d_in[3];
  const float* cent = (const float*)d_in[4];
  float* out = (float*)d_out;

  const size_t vtmpN = (size_t)BB * KK * DD;
  const size_t ssN   = (size_t)BB * KK;
  const size_t need  = ((size_t)TILES * KK * DD + (size_t)TILES * KK
                        + vtmpN + ssN) * sizeof(float);

  if (ws_size >= need) {
    float* pv    = (float*)d_ws;
    float* ps    = pv + (size_t)TILES * KK * DD;
    float* vtmp  = ps + (size_t)TILES * KK;
    float* ssbuf = vtmp + vtmpN;
    fused_kernel<<<TILES, 256, 0, stream>>>(x, mask, W, bias, pv, ps, 1);
    finalizeA_kernel<<<BB * KK, 256, 0, stream>>>(pv, ps, cent, vtmp, ssbuf, TPBAT);
    finalizeB_kernel<<<BB, 1024, 0, stream>>>(vtmp, ssbuf, out);
  } else {
    float* vacc  = (float*)d_ws;                 // [BB][KK][DD]
    float* sacc  = vacc + vtmpN;                 // [BB][KK]
    float* vtmp  = sacc + ssN;
    float* ssbuf = vtmp + vtmpN;
    hipMemsetAsync(d_ws, 0, (vtmpN + ssN) * sizeof(float), stream);
    fused_kernel<<<TILES, 256, 0, stream>>>(x, mask, W, bias, vacc, sacc, 0);
    finalizeA_kernel<<<BB * KK, 256, 0, stream>>>(vacc, sacc, cent, vtmp, ssbuf, 1);
    finalizeB_kernel<<<BB, 1024, 0, stream>>>(vtmp, ssbuf, out);
  }
}